// Round 4
// baseline (67.882 us; speedup 1.0000x reference)
//
#include <hip/hip_runtime.h>

#define SEQ 512
// alpha = log2(e)/sqrt(8); Q pre-scaled by sqrt(alpha) so score = exp2(q'.q')
#define SQRT_ALPHA     0.71419163f
#define INV_SQRT_ALPHA 1.40018452f

typedef _Float16 half4 __attribute__((ext_vector_type(4)));
typedef _Float16 half8 __attribute__((ext_vector_type(8)));
typedef _Float16 half2t __attribute__((ext_vector_type(2)));
typedef float f32x4 __attribute__((ext_vector_type(4)));

#define QT_S 516   // Qt dim-row stride in u16: 1032 B -> ~2-way banks, 8B-aligned

// Fully fused: quantum feature -> MFMA attention -> projection. No workspace.
// grid (8 b, 32 chunks of 16 rows), block 512 = 8 waves; wave = one head.
// Scores S = Q'.Q'^T symmetric => D-frag of mfma(Qfrag_T, Qfrag_R) reads back
// exactly as the A-frag of E for the PV matmul (no shuffles). Ones-column
// (lane lr==8, in-register) accumulates the softmax denominator for free.
__global__ __launch_bounds__(512) void qattn_fused(
    const float* __restrict__ x,      // fp32 [8,512,64]
    const float* __restrict__ theta,  // fp32 [8]
    const float* __restrict__ Wo,     // fp32 [64][64]
    const float* __restrict__ bo,     // fp32 [64]
    float* __restrict__ out)          // fp32 [4096][64]
{
    __shared__ _Float16 Qr[8 * SEQ * 8];   // 64 KB row-major  [h][t][d]
    __shared__ _Float16 Qt[8 * 8 * QT_S];  // 66 KB col-major  [h][d][t]
    __shared__ float    ctxs[16][68];      // 4.25 KB ctx staging (pitch 68)
    __shared__ float    Ws[64][68];        // 17 KB W_o staging

    const int b     = blockIdx.x;
    const int chunk = blockIdx.y;          // rows [16*chunk, +16)
    const int tid   = threadIdx.x;

    // stage W_o (8 f32/thread) — independent region, overlaps with build
    #pragma unroll
    for (int i = 0; i < 8; i++) {
        int idx = i * 512 + tid;
        Ws[idx >> 6][idx & 63] = Wo[idx];
    }

    float th[8];
    #pragma unroll
    for (int w = 0; w < 8; w++) th[w] = theta[w];

    // ---- build Q features: thread owns row s=tid, all 8 heads ----
    {
        const float* xp = x + ((size_t)(b * SEQ + tid) * 64);
        float4 xv[16];
        #pragma unroll
        for (int i = 0; i < 16; i++)
            xv[i] = reinterpret_cast<const float4*>(xp)[i];
        #pragma unroll
        for (int h = 0; h < 8; h++) {
            float4 xa = xv[2 * h], xb = xv[2 * h + 1];
            float c[8];
            c[0] = __cosf(xa.x + th[0]); c[1] = __cosf(xa.y + th[1]);
            c[2] = __cosf(xa.z + th[2]); c[3] = __cosf(xa.w + th[3]);
            c[4] = __cosf(xb.x + th[4]); c[5] = __cosf(xb.y + th[5]);
            c[6] = __cosf(xb.z + th[6]); c[7] = __cosf(xb.w + th[7]);
            float q[8];
            float pre = c[0];
            #pragma unroll
            for (int k = 1; k < 8; k++) { pre *= c[k]; q[k] = pre; }
            float suf = 1.f;
            #pragma unroll
            for (int w = 7; w >= 1; w--) suf *= c[w];
            q[0] = suf;
            half8 qh;
            #pragma unroll
            for (int k = 0; k < 8; k++) qh[k] = (_Float16)(q[k] * SQRT_ALPHA);
            *reinterpret_cast<half8*>(&Qr[(h * SEQ + tid) * 8]) = qh;
            #pragma unroll
            for (int d = 0; d < 8; d++) Qt[(h * 8 + d) * QT_S + tid] = qh[d];
        }
    }
    __syncthreads();

    // ---- per-wave MFMA attention: wave = head ----
    const int lane = tid & 63;
    const int h    = tid >> 6;            // 0..7
    const int lr   = lane & 15;           // fragment col / row index
    const int lg   = lane >> 4;           // k/row group

    // loop-invariant B-frag: rows of this chunk's 16-row block (X.X^T trick)
    half4 qb = (half4)0;
    if (lg < 2)
        qb = *reinterpret_cast<const half4*>(
            &Qr[(h * SEQ + chunk * 16 + lr) * 8 + lg * 4]);

    const _Float16* aP = &Qr[(h * SEQ + lr) * 8 + lg * 4];   // + T*128
    const _Float16* vP = &Qt[(h * 8 + lr) * QT_S + lg * 4];  // + T*16 (lr<8)

    f32x4 acc = {0.f, 0.f, 0.f, 0.f};
    #pragma unroll 8
    for (int T = 0; T < 32; T++) {
        half4 qa = (half4)0;
        if (lg < 2) qa = *reinterpret_cast<const half4*>(aP + T * 128);
        half4 vt;
        if (lr < 8)       vt = *reinterpret_cast<const half4*>(vP + T * 16);
        else if (lr == 8) vt = (half4){1.f16, 1.f16, 1.f16, 1.f16};
        else              vt = (half4)0;
        f32x4 sv = __builtin_amdgcn_mfma_f32_16x16x16f16(
            qa, qb, (f32x4){0.f, 0.f, 0.f, 0.f}, 0, 0, 0);
        // |score| <= 8*alpha = 4.08: exp2 safe without max-subtraction
        float e0 = __builtin_amdgcn_exp2f(sv.x);
        float e1 = __builtin_amdgcn_exp2f(sv.y);
        float e2 = __builtin_amdgcn_exp2f(sv.z);
        float e3 = __builtin_amdgcn_exp2f(sv.w);
        half2t p0 = __builtin_bit_cast(half2t, __builtin_amdgcn_cvt_pkrtz(e0, e1));
        half2t p1 = __builtin_bit_cast(half2t, __builtin_amdgcn_cvt_pkrtz(e2, e3));
        half4 ef = {p0.x, p0.y, p1.x, p1.y};  // D-layout == A-layout (S symm)
        acc = __builtin_amdgcn_mfma_f32_16x16x16f16(ef, vt, acc, 0, 0, 0);
    }

    // acc: lane (lg,lr), reg j -> ctx row chunk*16+lg*4+j, col lr (8 = denom)
    {
        const int src = (lane & 48) | 8;  // denominator lane of this row group
        float res[4];
        #pragma unroll
        for (int j = 0; j < 4; j++) {
            float lv = __shfl(acc[j], src, 64);
            res[j] = acc[j] * (INV_SQRT_ALPHA * __builtin_amdgcn_rcpf(lv));
        }
        if (lr < 8) {
            #pragma unroll
            for (int j = 0; j < 4; j++)
                ctxs[lg * 4 + j][h * 8 + lr] = res[j];
        }
    }
    __syncthreads();

    // ---- projection: out[t,e] = ctx[t,:].Wo[e,:] + bo[e]; 2 rows/thread ----
    {
        const int e  = tid & 63;
        const int wv = tid >> 6;
        const float bb = bo[e];
        #pragma unroll
        for (int r = 0; r < 2; r++) {
            const int row = wv * 2 + r;
            float a0 = 0.f;
            #pragma unroll 4
            for (int k4 = 0; k4 < 16; k4++) {
                float4 w  = *reinterpret_cast<const float4*>(&Ws[e][k4 * 4]);
                float4 cv = *reinterpret_cast<const float4*>(&ctxs[row][k4 * 4]);
                a0 += cv.x * w.x + cv.y * w.y + cv.z * w.z + cv.w * w.w;
            }
            out[(size_t)(b * SEQ + chunk * 16 + row) * 64 + e] = a0 + bb;
        }
    }
}

extern "C" void kernel_launch(void* const* d_in, const int* in_sizes, int n_in,
                              void* d_out, int out_size, void* d_ws, size_t ws_size,
                              hipStream_t stream) {
    const float* x     = (const float*)d_in[0];  // [8,512,64]
    const float* theta = (const float*)d_in[1];  // [8]
    const float* Wo    = (const float*)d_in[2];  // [64,64]
    const float* bo    = (const float*)d_in[3];  // [64]
    float* out = (float*)d_out;                  // [8,512,64]
    (void)d_ws; (void)ws_size;                   // workspace unused

    qattn_fused<<<dim3(8, 32), 512, 0, stream>>>(x, theta, Wo, bo, out);
}

// Round 5
// 66.665 us; speedup vs baseline: 1.0183x; 1.0183x over previous
//
#include <hip/hip_runtime.h>

#define SEQ 512
// alpha = log2(e)/sqrt(8); Q pre-scaled by sqrt(alpha) so score = exp2(q'.q')
#define SQRT_ALPHA     0.71419163f
#define INV_SQRT_ALPHA 1.40018452f

typedef _Float16 half4 __attribute__((ext_vector_type(4)));
typedef _Float16 half2t __attribute__((ext_vector_type(2)));
typedef float f32x4 __attribute__((ext_vector_type(4)));

// LDS strides in u16 units, chosen for bank spread + 8B alignment of b64 reads
#define QS_STRIDE 20    // 16 k-cols (8 data + 8 zeros for K=16 pad) + 4 pad
#define QT_STRIDE 524   // 512 t + 12 pad (stride*2 % 8 == 0, banks ~2-way)

// Kernel 1: MFMA quantum attention.
// Scores S = Q'.Q'^T are symmetric, so the D-fragment of mfma(Qfrag_T, Qfrag_R)
// (col=lane&15,row=4*(lane>>4)+reg) reads back EXACTLY as the A-fragment
// (row=lane&15,k=4*(lane>>4)+j) of E for the PV matmul: no shuffles.
// V = [Q' | 1 | 0...]: col 8 accumulates the softmax denominator for free.
// grid (64 pairs, 4), block 512 = 8 waves; wave owns 16-row block R = 8y+wv.
// Build is 1 row/thread (8 cos) -> minimal transcendental redundancy (4x/pair).
__global__ __launch_bounds__(512) void qattn_kernel(
    const float* __restrict__ x,      // fp32 [8,512,64]
    const float* __restrict__ theta,  // fp32 [8]
    float* __restrict__ ctx)          // fp32 [4096][64]
{
    __shared__ unsigned short Q16[SEQ * QS_STRIDE];   // 20480 B, A/B frags
    __shared__ unsigned short QT16[16 * QT_STRIDE];   // 16768 B, V^T (B frags)

    const int pair = blockIdx.x;      // b*8 + h
    const int b = pair >> 3, h = pair & 7;
    const int tid = threadIdx.x;

    float th[8];
    #pragma unroll
    for (int w = 0; w < 8; w++) th[w] = theta[w];

    // Build scaled Q in f16: one row per thread
    {
        const int s = tid;
        const float* xp = x + ((size_t)(b * SEQ + s) * 64 + h * 8);
        float4 xa = *reinterpret_cast<const float4*>(xp);
        float4 xb = *reinterpret_cast<const float4*>(xp + 4);
        float c[8];
        c[0] = __cosf(xa.x + th[0]); c[1] = __cosf(xa.y + th[1]);
        c[2] = __cosf(xa.z + th[2]); c[3] = __cosf(xa.w + th[3]);
        c[4] = __cosf(xb.x + th[4]); c[5] = __cosf(xb.y + th[5]);
        c[6] = __cosf(xb.z + th[6]); c[7] = __cosf(xb.w + th[7]);
        float q[8];
        float pre = c[0];
        #pragma unroll
        for (int k = 1; k < 8; k++) { pre *= c[k]; q[k] = pre; }
        float suf = 1.f;
        #pragma unroll
        for (int w = 7; w >= 1; w--) suf *= c[w];
        q[0] = suf;
        _Float16 qh[8];
        #pragma unroll
        for (int k = 0; k < 8; k++) qh[k] = (_Float16)(q[k] * SQRT_ALPHA);
        // row-major fragment source (k-cols 8..15 zero-padded for K=16)
        half4 lo = {qh[0], qh[1], qh[2], qh[3]};
        half4 hi = {qh[4], qh[5], qh[6], qh[7]};
        *reinterpret_cast<half4*>(&Q16[s * QS_STRIDE + 0])  = lo;
        *reinterpret_cast<half4*>(&Q16[s * QS_STRIDE + 4])  = hi;
        *reinterpret_cast<half4*>(&Q16[s * QS_STRIDE + 8])  = (half4)0;
        *reinterpret_cast<half4*>(&Q16[s * QS_STRIDE + 12]) = (half4)0;
        // transposed V for PV B-fragments: col-major, col 8 = ones
        #pragma unroll
        for (int c8 = 0; c8 < 8; c8++)
            *reinterpret_cast<_Float16*>(&QT16[c8 * QT_STRIDE + s]) = qh[c8];
        *reinterpret_cast<_Float16*>(&QT16[8 * QT_STRIDE + s]) = (_Float16)1.0f;
        #pragma unroll
        for (int c8 = 9; c8 < 16; c8++) QT16[c8 * QT_STRIDE + s] = 0;
    }
    __syncthreads();

    const int lane = tid & 63;
    const int wv   = tid >> 6;            // 0..7
    const int R    = blockIdx.y * 8 + wv; // 16-row block 0..31
    const int lr   = lane & 15;           // col index in fragments
    const int lg   = lane >> 4;           // k/row group

    // loop-invariant B-fragment for scores: rows of Q'-block R (X.X^T trick)
    half4 qb = *reinterpret_cast<const half4*>(
        &Q16[(R * 16 + lr) * QS_STRIDE + lg * 4]);

    const unsigned short* aptr = &Q16[lr * QS_STRIDE + lg * 4];
    const unsigned short* vptr = &QT16[lr * QT_STRIDE + lg * 4];

    f32x4 acc = {0.f, 0.f, 0.f, 0.f};
    #pragma unroll 8
    for (int T = 0; T < 32; T++) {
        half4 qa = *reinterpret_cast<const half4*>(aptr + T * 16 * QS_STRIDE);
        half4 vt = *reinterpret_cast<const half4*>(vptr + T * 16);
        f32x4 sv = __builtin_amdgcn_mfma_f32_16x16x16f16(
            qa, qb, (f32x4){0.f, 0.f, 0.f, 0.f}, 0, 0, 0);
        // |score| <= 8*alpha = 4.08: exp2 safe without max-subtraction
        float e0 = __builtin_amdgcn_exp2f(sv.x);
        float e1 = __builtin_amdgcn_exp2f(sv.y);
        float e2 = __builtin_amdgcn_exp2f(sv.z);
        float e3 = __builtin_amdgcn_exp2f(sv.w);
        half2t p0 = __builtin_bit_cast(half2t, __builtin_amdgcn_cvt_pkrtz(e0, e1));
        half2t p1 = __builtin_bit_cast(half2t, __builtin_amdgcn_cvt_pkrtz(e2, e3));
        half4 ef = {p0.x, p0.y, p1.x, p1.y};  // D-layout == A-layout (S symm)
        acc = __builtin_amdgcn_mfma_f32_16x16x16f16(ef, vt, acc, 0, 0, 0);
    }

    // acc: lane (lg,lr), reg j -> ctx row R*16+lg*4+j, col lr (8 = denom)
    const int src = (lane & 48) | 8;      // denominator lane of this row group
    float res[4];
    #pragma unroll
    for (int j = 0; j < 4; j++) {
        float lv = __shfl(acc[j], src, 64);
        res[j] = acc[j] * (INV_SQRT_ALPHA * __builtin_amdgcn_rcpf(lv));
    }
    if (lr < 8) {
        const int rowb = b * SEQ + R * 16 + lg * 4;
        #pragma unroll
        for (int j = 0; j < 4; j++)
            ctx[(size_t)(rowb + j) * 64 + h * 8 + lr] = res[j];
    }
}

// Kernel 2: out[t, e] = ctx[t, :] . W_o[e, :] + b_o[e]
// grid 512 x 256; wave handles 2 tokens (all 64 e per token)
__global__ __launch_bounds__(256) void proj_kernel(
    const float* __restrict__ ctx,    // fp32 [4096][64]
    const float* __restrict__ Wo,     // fp32 [64][64]
    const float* __restrict__ bo,     // fp32 [64]
    float* __restrict__ out)          // fp32 [4096][64]
{
    __shared__ float Ws[64][68];      // pitch 68: 16B-aligned rows, conflict-free b128
    const int tid = threadIdx.x;
    #pragma unroll
    for (int i = 0; i < 16; i++) {
        int idx = i * 256 + tid;
        Ws[idx >> 6][idx & 63] = Wo[idx];
    }
    __syncthreads();

    const int e  = tid & 63;
    const int tg = tid >> 6;
    const int t0 = blockIdx.x * 8 + tg * 2;

    const float4* c0 = reinterpret_cast<const float4*>(ctx + (size_t)t0 * 64);
    const float4* c1 = reinterpret_cast<const float4*>(ctx + (size_t)(t0 + 1) * 64);
    float a0 = 0.f, a1 = 0.f;
    #pragma unroll 4
    for (int k4 = 0; k4 < 16; k4++) {
        float4 w  = *reinterpret_cast<const float4*>(&Ws[e][k4 * 4]);
        float4 x0 = c0[k4];            // wave-uniform broadcast
        float4 x1 = c1[k4];
        a0 += x0.x*w.x + x0.y*w.y + x0.z*w.z + x0.w*w.w;
        a1 += x1.x*w.x + x1.y*w.y + x1.z*w.z + x1.w*w.w;
    }
    float bb = bo[e];
    out[(size_t)t0 * 64 + e]       = a0 + bb;
    out[(size_t)(t0 + 1) * 64 + e] = a1 + bb;
}

extern "C" void kernel_launch(void* const* d_in, const int* in_sizes, int n_in,
                              void* d_out, int out_size, void* d_ws, size_t ws_size,
                              hipStream_t stream) {
    const float* x     = (const float*)d_in[0];  // [8,512,64]
    const float* theta = (const float*)d_in[1];  // [8]
    const float* Wo    = (const float*)d_in[2];  // [64,64]
    const float* bo    = (const float*)d_in[3];  // [64]
    float* out = (float*)d_out;                  // [8,512,64]
    float* ctx = (float*)d_ws;                   // 1 MB fp32 scratch

    qattn_kernel<<<dim3(64, 4), 512, 0, stream>>>(x, theta, ctx);
    proj_kernel<<<512, 256, 0, stream>>>(ctx, Wo, bo, out);
}